// Round 4
// baseline (343.357 us; speedup 1.0000x reference)
//
#include <hip/hip_runtime.h>
#include <hip/hip_bf16.h>

#define NNODE 1024
#define DIM 128
#define HEADS 8
#define DK 16
#define EDIM 16
#define BN 8               // target nodes per attn block
#define MR 32              // source rows per attn block (one-shot, no chunk loop)
#define KV_ROW 160         // k/v LDS row stride dwords = 8 h * 20
#define H_STRIDE 20        // 16 f32 + 4 pad: 20h mod 32 distinct for h=0..7 -> conflict-free
#define LOG2E 1.44269504f

__device__ __forceinline__ void async_copy16(const float* g, float* l) {
    __builtin_amdgcn_global_load_lds(
        (const __attribute__((address_space(1))) void*)g,
        (__attribute__((address_space(3))) void*)l, 16, 0, 0);
}

// ---------------- Kernel 1: LayerNorm + QKV projection ----------------
__global__ __launch_bounds__(384)
void ln_qkv_kernel(const float* __restrict__ x,
                   const float* __restrict__ Wq, const float* __restrict__ bq,
                   const float* __restrict__ Wk, const float* __restrict__ bk,
                   const float* __restrict__ Wv, const float* __restrict__ bv,
                   const float* __restrict__ gamma, const float* __restrict__ beta,
                   float* __restrict__ qg, float* __restrict__ kg, float* __restrict__ vg) {
    const int n = blockIdx.x;
    const int t = threadIdx.x;
    __shared__ float hrow[DIM];
    __shared__ float part[4];

    float xv = 0.f;
    if (t < 128) {
        xv = x[n * DIM + t];
        float v = xv;
        #pragma unroll
        for (int off = 32; off >= 1; off >>= 1) v += __shfl_xor(v, off);
        if ((t & 63) == 0) part[t >> 6] = v;
    }
    __syncthreads();
    const float mu = (part[0] + part[1]) * (1.0f / DIM);
    const float dx = xv - mu;
    if (t < 128) {
        float v = dx * dx;
        #pragma unroll
        for (int off = 32; off >= 1; off >>= 1) v += __shfl_xor(v, off);
        if ((t & 63) == 0) part[2 + (t >> 6)] = v;
    }
    __syncthreads();
    if (t < 128) {
        const float var = (part[2] + part[3]) * (1.0f / DIM);
        hrow[t] = dx * rsqrtf(var + 1e-5f) * gamma[t] + beta[t];
    }
    __syncthreads();

    const int which = t >> 7;          // 0,1,2 -> q,k,v (wave-uniform)
    const int col = t & 127;
    const float* W = (which == 0) ? Wq : (which == 1) ? Wk : Wv;
    const float* b = (which == 0) ? bq : (which == 1) ? bk : bv;
    float* o       = (which == 0) ? qg : (which == 1) ? kg : vg;
    float acc = b[col];
    #pragma unroll 16
    for (int i = 0; i < DIM; ++i) acc = fmaf(hrow[i], W[i * DIM + col], acc);
    o[n * DIM + col] = acc;
}

// ---------------- Kernel 2: one-shot attention partial, atomics out ----------------
// grid = (1024/BN) * 32 = 4096 blocks; 256 threads = (s: t>>5, np: (t>>3)&3, h: t&7)
// Block covers nodes [n0,n0+8) x m in [mb, mb+32). Thread handles n=np and n=np+4
// (k/v LDS reads amortized over the n-pair). Everything staged once; no chunk loop.
__global__ __launch_bounds__(256, 2)
void attn_kernel(const float* __restrict__ qg, const float* __restrict__ kg,
                 const float* __restrict__ vg, const float* __restrict__ ef,
                 const int* __restrict__ mask,
                 const float* __restrict__ Wae, const float* __restrict__ bae,
                 float* __restrict__ acc) {
    const int t = threadIdx.x;
    const int s  = t >> 5;        // 0..7 m sub-slot
    const int np = (t >> 3) & 3;  // n-pair id
    const int h  = t & 7;         // head
    const int wid = t >> 6, lane = t & 63;
    const int bx = blockIdx.x;
    const int n0 = (bx >> 5) * BN;
    const int mb = (bx & 31) * MR;

    __shared__ float ef_lds[BN * MR * EDIM];    // 16 KB, layout [nn][mm][16] (DMA order)
    __shared__ float kv_buf[2 * MR * KV_ROW];   // 40 KB; reduction scratch overlays later
    __shared__ int   mk_lds[BN * 34];

    float* k_lds = kv_buf;
    float* v_lds = kv_buf + MR * KV_ROW;

    // --- async ef stage: 16 segments of 1 KB (16 m-rows x 16 f32), 4 per wave ---
    #pragma unroll
    for (int i = 0; i < 4; ++i) {
        const int g = wid * 4 + i;
        const int nn = g >> 1, hf = g & 1;
        const float* gsrc = ef + ((size_t)(n0 + nn) * NNODE + (mb + hf * 16)) * EDIM + lane * 4;
        float* ldst = &ef_lds[(nn * MR + hf * 16) * EDIM + lane * 4];
        async_copy16(gsrc, ldst);
    }
    // --- k/v stage (transient registers) into padded [mm][h][20] layout ---
    #pragma unroll
    for (int r = 0; r < 4; ++r) {
        const int idx = t + 256 * r;        // 0..1023 16B-chunks
        const int mm = idx >> 5, c4 = idx & 31;
        const int hh = c4 >> 2, d4 = c4 & 3;
        const float4 kq = *(const float4*)(kg + (size_t)(mb + mm) * DIM + c4 * 4);
        const float4 vq = *(const float4*)(vg + (size_t)(mb + mm) * DIM + c4 * 4);
        *(float4*)&k_lds[mm * KV_ROW + hh * H_STRIDE + d4 * 4] = kq;
        *(float4*)&v_lds[mm * KV_ROW + hh * H_STRIDE + d4 * 4] = vq;
    }
    // --- mask stage ---
    {
        const int nn = t >> 5, mm = t & 31;
        mk_lds[nn * 34 + mm] = mask[(size_t)(n0 + nn) * NNODE + (mb + mm)];
    }
    // --- per-thread constants (global, L2-hot) ---
    float qreg[2][DK];
    #pragma unroll
    for (int hf = 0; hf < 2; ++hf) {
        const float* qp = qg + (size_t)(n0 + np + 4 * hf) * DIM + h * DK;
        #pragma unroll
        for (int d4 = 0; d4 < 4; ++d4) {
            const float4 qv = *(const float4*)(qp + d4 * 4);
            qreg[hf][d4 * 4 + 0] = qv.x; qreg[hf][d4 * 4 + 1] = qv.y;
            qreg[hf][d4 * 4 + 2] = qv.z; qreg[hf][d4 * 4 + 3] = qv.w;
        }
    }
    float waec[EDIM];
    #pragma unroll
    for (int e = 0; e < EDIM; ++e) waec[e] = Wae[e * HEADS + h] * LOG2E;
    const float baeh = bae[h] * LOG2E;

    float sl[2] = {0.f, 0.f};
    float accv[2][DK], accT[2][EDIM];
    #pragma unroll
    for (int hf = 0; hf < 2; ++hf) {
        #pragma unroll
        for (int d = 0; d < DK; ++d) accv[hf][d] = 0.f;
        #pragma unroll
        for (int e = 0; e < EDIM; ++e) accT[hf][e] = 0.f;
    }

    __syncthreads();   // barrier drains vmcnt (DMA) + lgkm (ds_write) per compiler semantics

    // --- compute: 4 m per thread, n-pair per m ---
    #pragma unroll
    for (int j = 0; j < 4; ++j) {
        const int m = j * 8 + s;
        float kk[DK], vv[DK];
        const float* kp = &k_lds[m * KV_ROW + h * H_STRIDE];
        const float* vp = &v_lds[m * KV_ROW + h * H_STRIDE];
        #pragma unroll
        for (int d4 = 0; d4 < 4; ++d4) {
            const float4 k4 = *(const float4*)(kp + d4 * 4);
            kk[d4 * 4 + 0] = k4.x; kk[d4 * 4 + 1] = k4.y;
            kk[d4 * 4 + 2] = k4.z; kk[d4 * 4 + 3] = k4.w;
            const float4 v4 = *(const float4*)(vp + d4 * 4);
            vv[d4 * 4 + 0] = v4.x; vv[d4 * 4 + 1] = v4.y;
            vv[d4 * 4 + 2] = v4.z; vv[d4 * 4 + 3] = v4.w;
        }
        #pragma unroll
        for (int hf = 0; hf < 2; ++hf) {
            const int n = np + 4 * hf;
            float efv[EDIM];
            #pragma unroll
            for (int q4 = 0; q4 < 4; ++q4) {
                const int e4 = (q4 + np) & 3;   // rotation -> conflict-free
                const float4 ev = *(const float4*)&ef_lds[(n * MR + m) * EDIM + e4 * 4];
                efv[e4 * 4 + 0] = ev.x; efv[e4 * 4 + 1] = ev.y;
                efv[e4 * 4 + 2] = ev.z; efv[e4 * 4 + 3] = ev.w;
            }
            float bias = baeh, dot = 0.f;
            #pragma unroll
            for (int e = 0; e < EDIM; ++e) bias = fmaf(efv[e], waec[e], bias);
            #pragma unroll
            for (int d = 0; d < DK; ++d) dot = fmaf(qreg[hf][d], kk[d], dot);
            // p = exp(dot/4 + bias_raw) computed as exp2 with pre-scaled constants
            const float lg = fmaf(dot, 0.25f * LOG2E, bias);
            const float p = mk_lds[n * 34 + m] ? exp2f(lg) : 0.f;  // masked == exact 0, as ref
            sl[hf] += p;
            #pragma unroll
            for (int d = 0; d < DK; ++d) accv[hf][d] = fmaf(p, vv[d], accv[hf][d]);
            #pragma unroll
            for (int e = 0; e < EDIM; ++e) accT[hf][e] = fmaf(p, efv[e], accT[hf][e]);
        }
    }

    // --- reduce s-pairs within wave (lane ^ 32) ---
    #pragma unroll
    for (int hf = 0; hf < 2; ++hf) {
        sl[hf] += __shfl_xor(sl[hf], 32);
        #pragma unroll
        for (int d = 0; d < DK; ++d) accv[hf][d] += __shfl_xor(accv[hf][d], 32);
        #pragma unroll
        for (int e = 0; e < EDIM; ++e) accT[hf][e] += __shfl_xor(accT[hf][e], 32);
    }
    __syncthreads();                 // k/v reads done -> safe to overlay reduction scratch
    float* red = kv_buf;             // [w4][np4][h8][hf2][33] = 8448 f32 (fits in 10240)
    if (lane < 32) {
        float* rp = &red[((wid * 4 + np) * 8 + h) * 66];
        #pragma unroll
        for (int hf = 0; hf < 2; ++hf) {
            rp[hf * 33 + 0] = sl[hf];
            #pragma unroll
            for (int d = 0; d < DK; ++d) rp[hf * 33 + 1 + d] = accv[hf][d];
            #pragma unroll
            for (int e = 0; e < EDIM; ++e) rp[hf * 33 + 17 + e] = accT[hf][e];
        }
    }
    __syncthreads();
    // --- combine 4 wave copies, one atomicAdd per value ---
    for (int v = t; v < BN * HEADS * 33; v += 256) {   // 2112 values
        const int n = v / 264;
        const int rem = v - n * 264;
        const int hh = rem / 33;
        const int idx = rem - hh * 33;
        const int nnp = n & 3, hf = n >> 2;
        float sum = 0.f;
        #pragma unroll
        for (int w = 0; w < 4; ++w)
            sum += red[((w * 4 + nnp) * 8 + hh) * 66 + hf * 33 + idx];
        atomicAdd(&acc[((size_t)(n0 + n) * HEADS + hh) * 33 + idx], sum);
    }
}

// ---------------- Kernel 3: epilogue (Wve, normalize, Wo, residual) ----------------
__global__ __launch_bounds__(128)
void final_kernel(const float* __restrict__ acc,
                  const float* __restrict__ Wve, const float* __restrict__ bve,
                  const float* __restrict__ x,
                  const float* __restrict__ Wo, const float* __restrict__ bo,
                  float* __restrict__ out) {
    const int n = blockIdx.x, t = threadIdx.x;
    __shared__ float ab[HEADS * 33];
    __shared__ float orow[DIM];
    for (int u = t; u < HEADS * 33; u += 128) ab[u] = acc[(size_t)n * HEADS * 33 + u];
    __syncthreads();
    const int col = t, hh = col >> 4, dd = col & 15;
    const float slv = ab[hh * 33];
    float acc2 = 0.f;
    #pragma unroll
    for (int e = 0; e < EDIM; ++e) acc2 = fmaf(ab[hh * 33 + 17 + e], Wve[e * DIM + col], acc2);
    orow[col] = (ab[hh * 33 + 1 + dd] + acc2) / slv + bve[col];
    __syncthreads();
    float o = bo[col] + x[(size_t)n * DIM + col];
    #pragma unroll 16
    for (int i = 0; i < DIM; ++i) o = fmaf(orow[i], Wo[i * DIM + col], o);
    out[(size_t)n * DIM + col] = o;
}

extern "C" void kernel_launch(void* const* d_in, const int* in_sizes, int n_in,
                              void* d_out, int out_size, void* d_ws, size_t ws_size,
                              hipStream_t stream) {
    const float* x     = (const float*)d_in[0];
    const float* ef    = (const float*)d_in[1];
    const int*   mask  = (const int*)d_in[2];
    const float* Wq    = (const float*)d_in[3];
    const float* bq    = (const float*)d_in[4];
    const float* Wk    = (const float*)d_in[5];
    const float* bk    = (const float*)d_in[6];
    const float* Wv    = (const float*)d_in[7];
    const float* bv    = (const float*)d_in[8];
    const float* Wae   = (const float*)d_in[9];
    const float* bae   = (const float*)d_in[10];
    const float* Wve   = (const float*)d_in[11];
    const float* bve   = (const float*)d_in[12];
    const float* Wo    = (const float*)d_in[13];
    const float* bo    = (const float*)d_in[14];
    const float* gamma = (const float*)d_in[15];
    const float* beta  = (const float*)d_in[16];

    float* ws = (float*)d_ws;
    float* accb = ws;                                   // 1024*8*33 = 270336 f32
    float* qg   = ws + 270336;
    float* kg   = qg + (size_t)NNODE * DIM;
    float* vg   = kg + (size_t)NNODE * DIM;

    hipMemsetAsync(accb, 0, (size_t)NNODE * HEADS * 33 * sizeof(float), stream);
    ln_qkv_kernel<<<NNODE, 384, 0, stream>>>(x, Wq, bq, Wk, bk, Wv, bv, gamma, beta, qg, kg, vg);
    attn_kernel<<<(NNODE / BN) * 32, 256, 0, stream>>>(qg, kg, vg, ef, mask, Wae, bae, accb);
    final_kernel<<<NNODE, 128, 0, stream>>>(accb, Wve, bve, x, Wo, bo, (float*)d_out);
}

// Round 5
// 183.300 us; speedup vs baseline: 1.8732x; 1.8732x over previous
//
#include <hip/hip_runtime.h>
#include <hip/hip_bf16.h>

#define NNODE 1024
#define DIM 128
#define HEADS 8
#define DK 16
#define EDIM 16
#define BN 8               // target nodes per attn block
#define MR 32              // source rows per attn block (one-shot, no chunk loop)
#define KV_ROW 160         // k/v LDS row stride dwords = 8 h * 20
#define H_STRIDE 20        // 20h mod 32 distinct for h=0..7 -> conflict-free reads
#define EF_ROW 20          // ef m-stride (dwords)
#define EF_NSTR 644        // ef n-stride = 32*20+4: skews banks by 4 per n -> conflict-free
#define LOG2E 1.44269504f

// ---------------- Kernel 1: LayerNorm + QKV projection ----------------
__global__ __launch_bounds__(384)
void ln_qkv_kernel(const float* __restrict__ x,
                   const float* __restrict__ Wq, const float* __restrict__ bq,
                   const float* __restrict__ Wk, const float* __restrict__ bk,
                   const float* __restrict__ Wv, const float* __restrict__ bv,
                   const float* __restrict__ gamma, const float* __restrict__ beta,
                   float* __restrict__ qg, float* __restrict__ kg, float* __restrict__ vg) {
    const int n = blockIdx.x;
    const int t = threadIdx.x;
    __shared__ float hrow[DIM];
    __shared__ float part[4];

    float xv = 0.f;
    if (t < 128) {
        xv = x[n * DIM + t];
        float v = xv;
        #pragma unroll
        for (int off = 32; off >= 1; off >>= 1) v += __shfl_xor(v, off);
        if ((t & 63) == 0) part[t >> 6] = v;
    }
    __syncthreads();
    const float mu = (part[0] + part[1]) * (1.0f / DIM);
    const float dx = xv - mu;
    if (t < 128) {
        float v = dx * dx;
        #pragma unroll
        for (int off = 32; off >= 1; off >>= 1) v += __shfl_xor(v, off);
        if ((t & 63) == 0) part[2 + (t >> 6)] = v;
    }
    __syncthreads();
    if (t < 128) {
        const float var = (part[2] + part[3]) * (1.0f / DIM);
        hrow[t] = dx * rsqrtf(var + 1e-5f) * gamma[t] + beta[t];
    }
    __syncthreads();

    const int which = t >> 7;          // 0,1,2 -> q,k,v (wave-uniform)
    const int col = t & 127;
    const float* W = (which == 0) ? Wq : (which == 1) ? Wk : Wv;
    const float* b = (which == 0) ? bq : (which == 1) ? bk : bv;
    float* o       = (which == 0) ? qg : (which == 1) ? kg : vg;
    float acc = b[col];
    #pragma unroll 16
    for (int i = 0; i < DIM; ++i) acc = fmaf(hrow[i], W[i * DIM + col], acc);
    o[n * DIM + col] = acc;
}

// ---------------- Kernel 2: one-shot attention partial, atomics out ----------------
// grid = (1024/BN)*32 = 4096 blocks; 256 threads = (s: t>>5, np: (t>>3)&3, h: t&7)
// Thread handles n = np and n = np+4 (k/v LDS reads amortized over the n-pair).
// ALL register-array indices are compile-time constants (round-4 lesson: a runtime
// index into a register array explodes into v_cndmask chains, 20x VALU bloat).
__global__ __launch_bounds__(256, 2)
void attn_kernel(const float* __restrict__ qg, const float* __restrict__ kg,
                 const float* __restrict__ vg, const float* __restrict__ ef,
                 const int* __restrict__ mask,
                 const float* __restrict__ Wae, const float* __restrict__ bae,
                 float* __restrict__ acc) {
    const int t = threadIdx.x;
    const int s  = t >> 5;        // 0..7 m sub-slot
    const int np = (t >> 3) & 3;  // n-pair id
    const int h  = t & 7;         // head
    const int wid = t >> 6, lane = t & 63;
    const int bx = blockIdx.x;
    const int n0 = (bx >> 5) * BN;
    const int mb = (bx & 31) * MR;

    __shared__ float ef_lds[BN * EF_NSTR];      // 20.6 KB, skewed layout
    __shared__ float kv_buf[2 * MR * KV_ROW];   // 40 KB; reduction scratch overlays later
    __shared__ int   mk_lds[BN * 34];

    float* k_lds = kv_buf;
    float* v_lds = kv_buf + MR * KV_ROW;

    // --- ef stage: 1024 float4 chunks, 4 per thread, into skewed layout ---
    #pragma unroll
    for (int r = 0; r < 4; ++r) {
        const int idx = t + 256 * r;            // 0..1023
        const int nn = idx >> 7;                // 0..7
        const int mm = (idx >> 2) & 31;
        const int q4 = idx & 3;
        const float4 ev = *(const float4*)(ef + ((size_t)(n0 + nn) * NNODE + mb + mm) * EDIM + q4 * 4);
        *(float4*)&ef_lds[nn * EF_NSTR + mm * EF_ROW + q4 * 4] = ev;
    }
    // --- k/v stage into padded [mm][h][20] layout ---
    #pragma unroll
    for (int r = 0; r < 4; ++r) {
        const int idx = t + 256 * r;            // 0..1023 16B-chunks
        const int mm = idx >> 5, c4 = idx & 31;
        const int hh = c4 >> 2, d4 = c4 & 3;
        const float4 kq = *(const float4*)(kg + (size_t)(mb + mm) * DIM + c4 * 4);
        const float4 vq = *(const float4*)(vg + (size_t)(mb + mm) * DIM + c4 * 4);
        *(float4*)&k_lds[mm * KV_ROW + hh * H_STRIDE + d4 * 4] = kq;
        *(float4*)&v_lds[mm * KV_ROW + hh * H_STRIDE + d4 * 4] = vq;
    }
    // --- mask stage ---
    {
        const int nn = t >> 5, mm = t & 31;
        mk_lds[nn * 34 + mm] = mask[(size_t)(n0 + nn) * NNODE + (mb + mm)];
    }
    // --- per-thread constants (global, L2-hot) ---
    float qreg[2][DK];
    #pragma unroll
    for (int hf = 0; hf < 2; ++hf) {
        const float* qp = qg + (size_t)(n0 + np + 4 * hf) * DIM + h * DK;
        #pragma unroll
        for (int d4 = 0; d4 < 4; ++d4) {
            const float4 qv = *(const float4*)(qp + d4 * 4);
            qreg[hf][d4 * 4 + 0] = qv.x; qreg[hf][d4 * 4 + 1] = qv.y;
            qreg[hf][d4 * 4 + 2] = qv.z; qreg[hf][d4 * 4 + 3] = qv.w;
        }
    }
    float waec[EDIM];
    #pragma unroll
    for (int e = 0; e < EDIM; ++e) waec[e] = Wae[e * HEADS + h] * LOG2E;
    const float baeh = bae[h] * LOG2E;

    float sl[2] = {0.f, 0.f};
    float accv[2][DK], accT[2][EDIM];
    #pragma unroll
    for (int hf = 0; hf < 2; ++hf) {
        #pragma unroll
        for (int d = 0; d < DK; ++d) accv[hf][d] = 0.f;
        #pragma unroll
        for (int e = 0; e < EDIM; ++e) accT[hf][e] = 0.f;
    }

    __syncthreads();

    // --- compute: 4 m per thread, n-pair per m; all indices static ---
    #pragma unroll
    for (int j = 0; j < 4; ++j) {
        const int m = j * 8 + s;
        float kk[DK], vv[DK];
        const float* kp = &k_lds[m * KV_ROW + h * H_STRIDE];
        const float* vp = &v_lds[m * KV_ROW + h * H_STRIDE];
        #pragma unroll
        for (int d4 = 0; d4 < 4; ++d4) {
            const float4 k4 = *(const float4*)(kp + d4 * 4);
            kk[d4 * 4 + 0] = k4.x; kk[d4 * 4 + 1] = k4.y;
            kk[d4 * 4 + 2] = k4.z; kk[d4 * 4 + 3] = k4.w;
            const float4 v4 = *(const float4*)(vp + d4 * 4);
            vv[d4 * 4 + 0] = v4.x; vv[d4 * 4 + 1] = v4.y;
            vv[d4 * 4 + 2] = v4.z; vv[d4 * 4 + 3] = v4.w;
        }
        #pragma unroll
        for (int hf = 0; hf < 2; ++hf) {
            const int n = np + 4 * hf;
            const float* ep = &ef_lds[n * EF_NSTR + m * EF_ROW];
            float efv[EDIM];
            #pragma unroll
            for (int e4 = 0; e4 < 4; ++e4) {       // STATIC e4 (skew handles banks)
                const float4 ev = *(const float4*)(ep + e4 * 4);
                efv[e4 * 4 + 0] = ev.x; efv[e4 * 4 + 1] = ev.y;
                efv[e4 * 4 + 2] = ev.z; efv[e4 * 4 + 3] = ev.w;
            }
            float bias = baeh, dot = 0.f;
            #pragma unroll
            for (int e = 0; e < EDIM; ++e) bias = fmaf(efv[e], waec[e], bias);
            #pragma unroll
            for (int d = 0; d < DK; ++d) dot = fmaf(qreg[hf][d], kk[d], dot);
            const float lg = fmaf(dot, 0.25f * LOG2E, bias);
            const float p = mk_lds[n * 34 + m] ? __builtin_amdgcn_exp2f(lg) : 0.f;
            sl[hf] += p;
            #pragma unroll
            for (int d = 0; d < DK; ++d) accv[hf][d] = fmaf(p, vv[d], accv[hf][d]);
            #pragma unroll
            for (int e = 0; e < EDIM; ++e) accT[hf][e] = fmaf(p, efv[e], accT[hf][e]);
        }
    }

    // --- reduce s-pairs within wave (lane ^ 32) ---
    #pragma unroll
    for (int hf = 0; hf < 2; ++hf) {
        sl[hf] += __shfl_xor(sl[hf], 32);
        #pragma unroll
        for (int d = 0; d < DK; ++d) accv[hf][d] += __shfl_xor(accv[hf][d], 32);
        #pragma unroll
        for (int e = 0; e < EDIM; ++e) accT[hf][e] += __shfl_xor(accT[hf][e], 32);
    }
    __syncthreads();                 // k/v reads done -> safe to overlay reduction scratch
    float* red = kv_buf;             // [w4][np4][h8][hf2][33] = 8448 f32 (fits in 10240)
    if (lane < 32) {
        float* rp = &red[((wid * 4 + np) * 8 + h) * 66];
        #pragma unroll
        for (int hf = 0; hf < 2; ++hf) {
            rp[hf * 33 + 0] = sl[hf];
            #pragma unroll
            for (int d = 0; d < DK; ++d) rp[hf * 33 + 1 + d] = accv[hf][d];
            #pragma unroll
            for (int e = 0; e < EDIM; ++e) rp[hf * 33 + 17 + e] = accT[hf][e];
        }
    }
    __syncthreads();
    // --- combine 4 wave copies, one atomicAdd per value ---
    for (int v = t; v < BN * HEADS * 33; v += 256) {   // 2112 values
        const int n = v / 264;
        const int rem = v - n * 264;
        const int hh = rem / 33;
        const int idx = rem - hh * 33;
        const int nnp = n & 3, hf = n >> 2;
        float sum = 0.f;
        #pragma unroll
        for (int w = 0; w < 4; ++w)
            sum += red[((w * 4 + nnp) * 8 + hh) * 66 + hf * 33 + idx];
        atomicAdd(&acc[((size_t)(n0 + n) * HEADS + hh) * 33 + idx], sum);
    }
}

// ---------------- Kernel 3: epilogue (Wve, normalize, Wo, residual) ----------------
__global__ __launch_bounds__(128)
void final_kernel(const float* __restrict__ acc,
                  const float* __restrict__ Wve, const float* __restrict__ bve,
                  const float* __restrict__ x,
                  const float* __restrict__ Wo, const float* __restrict__ bo,
                  float* __restrict__ out) {
    const int n = blockIdx.x, t = threadIdx.x;
    __shared__ float ab[HEADS * 33];
    __shared__ float orow[DIM];
    for (int u = t; u < HEADS * 33; u += 128) ab[u] = acc[(size_t)n * HEADS * 33 + u];
    __syncthreads();
    const int col = t, hh = col >> 4, dd = col & 15;
    const float slv = ab[hh * 33];
    float acc2 = 0.f;
    #pragma unroll
    for (int e = 0; e < EDIM; ++e) acc2 = fmaf(ab[hh * 33 + 17 + e], Wve[e * DIM + col], acc2);
    orow[col] = (ab[hh * 33 + 1 + dd] + acc2) / slv + bve[col];
    __syncthreads();
    float o = bo[col] + x[(size_t)n * DIM + col];
    #pragma unroll 16
    for (int i = 0; i < DIM; ++i) o = fmaf(orow[i], Wo[i * DIM + col], o);
    out[(size_t)n * DIM + col] = o;
}

extern "C" void kernel_launch(void* const* d_in, const int* in_sizes, int n_in,
                              void* d_out, int out_size, void* d_ws, size_t ws_size,
                              hipStream_t stream) {
    const float* x     = (const float*)d_in[0];
    const float* ef    = (const float*)d_in[1];
    const int*   mask  = (const int*)d_in[2];
    const float* Wq    = (const float*)d_in[3];
    const float* bq    = (const float*)d_in[4];
    const float* Wk    = (const float*)d_in[5];
    const float* bk    = (const float*)d_in[6];
    const float* Wv    = (const float*)d_in[7];
    const float* bv    = (const float*)d_in[8];
    const float* Wae   = (const float*)d_in[9];
    const float* bae   = (const float*)d_in[10];
    const float* Wve   = (const float*)d_in[11];
    const float* bve   = (const float*)d_in[12];
    const float* Wo    = (const float*)d_in[13];
    const float* bo    = (const float*)d_in[14];
    const float* gamma = (const float*)d_in[15];
    const float* beta  = (const float*)d_in[16];

    float* ws = (float*)d_ws;
    float* accb = ws;                                   // 1024*8*33 = 270336 f32
    float* qg   = ws + 270336;
    float* kg   = qg + (size_t)NNODE * DIM;
    float* vg   = kg + (size_t)NNODE * DIM;

    hipMemsetAsync(accb, 0, (size_t)NNODE * HEADS * 33 * sizeof(float), stream);
    ln_qkv_kernel<<<NNODE, 384, 0, stream>>>(x, Wq, bq, Wk, bk, Wv, bv, gamma, beta, qg, kg, vg);
    attn_kernel<<<(NNODE / BN) * 32, 256, 0, stream>>>(qg, kg, vg, ef, mask, Wae, bae, accb);
    final_kernel<<<NNODE, 128, 0, stream>>>(accb, Wve, bve, x, Wo, bo, (float*)d_out);
}